// Round 3
// baseline (427.499 us; speedup 1.0000x reference)
//
#include <hip/hip_runtime.h>

namespace {

constexpr int WS  = 11;
constexpr int RAD = 5;
constexpr int OT  = 32;            // output tile (square)
constexpr int HR  = OT + 2 * RAD;  // 42 h-rows per tile
constexpr float SSIM_C1 = 0.01f * 0.01f;
constexpr float SSIM_C2 = 0.03f * 0.03f;

// gaussian(sigma=1.5, ws=11); constexpr so unrolled accesses fold to literals
__device__ constexpr float GW[WS] = {
    0.00102838f, 0.00759876f, 0.03600077f, 0.10936069f, 0.21300553f,
    0.26601172f, 0.21300553f, 0.10936069f, 0.03600077f, 0.00759876f,
    0.00102838f};

// transposed h layout: logical (c in 0..31, r in 0..41) -> word c*44 + ((c>>3)<<2) + r
// stride 44 (176B, 16B-aligned rows); extra 16B skew per 8 columns de-phases the
// 128B bank window so 16-lane ds_read_b128 groups hit distinct 16B slots.
constexpr int HWORDS = 32 * 44 + 16;   // 1424 words per quantity
__device__ __forceinline__ int hoff(int c) { return c * 44 + ((c >> 3) << 2); }

__global__ void init_out(float* out) { out[0] = 1.0f; }

template <bool POOL>
__global__ __launch_bounds__(256, 4)
void ssim_kernel(const float* __restrict__ X, const float* __restrict__ Y,
                 float* __restrict__ out, float coef,
                 float* __restrict__ PX, float* __restrict__ PY,
                 int H, int W)
{
    __shared__ float h[5][HWORDS];   // hx, hy, hxx, hyy, hxy (transposed)
    __shared__ float red[4];

    const int tid = threadIdx.x;
    const int n  = blockIdx.z;
    const int by = blockIdx.y * OT;
    const int bx = blockIdx.x * OT;
    const size_t plane = (size_t)H * W;
    const float* Xn = X + (size_t)n * plane;
    const float* Yn = Y + (size_t)n * plane;

    // ---- fused 2x2 avg-pool for next scale (global reads, L1-hot) ----
    if (POOL) {
        int pr = tid >> 4, pc = tid & 15;          // 16x16 pooled px per block
        int gr = by + 2 * pr, gc = bx + 2 * pc;
        const float* x0 = Xn + (size_t)gr * W + gc;
        const float* y0 = Yn + (size_t)gr * W + gc;
        float2 xa = *(const float2*)x0, xb = *(const float2*)(x0 + W);
        float2 ya = *(const float2*)y0, yb = *(const float2*)(y0 + W);
        int Wp = W >> 1;
        size_t po = (size_t)n * (size_t)(H >> 1) * Wp
                  + (size_t)((by >> 1) + pr) * Wp + ((bx >> 1) + pc);
        PX[po] = 0.25f * (xa.x + xa.y + xb.x + xb.y);
        PY[po] = 0.25f * (ya.x + ya.y + yb.x + yb.y);
    }

    // ---- horizontal pass: global->regs sliding window, 4 cols/thread ----
    // task idx = c0*42 + r  (consecutive lanes share c0, walk r -> conflict-free
    // LDS writes; global reads hit L1 via inter-task overlap)
    for (int idx = tid; idx < 8 * HR; idx += 256) {
        int c0 = idx / HR;                 // 0..7  (output cols 4c0..4c0+3)
        int r  = idx - c0 * HR;            // 0..41
        int gr = by + r - RAD;
        bool rok = (unsigned)gr < (unsigned)H;
        const float* xrow = Xn + (size_t)gr * W;
        const float* yrow = Yn + (size_t)gr * W;
        int gb = bx + 4 * c0 - 8;          // 4-aligned; W multiple of 4 ->
                                           // each float4 fully in or fully out
        float fx[20], fy[20];
        #pragma unroll
        for (int m = 0; m < 5; ++m) {
            int gc = gb + 4 * m;
            float4 vx = make_float4(0.f, 0.f, 0.f, 0.f);
            float4 vy = make_float4(0.f, 0.f, 0.f, 0.f);
            if (rok && (unsigned)gc < (unsigned)W) {
                vx = *(const float4*)(xrow + gc);
                vy = *(const float4*)(yrow + gc);
            }
            fx[4*m] = vx.x; fx[4*m+1] = vx.y; fx[4*m+2] = vx.z; fx[4*m+3] = vx.w;
            fy[4*m] = vy.x; fy[4*m+1] = vy.y; fy[4*m+2] = vy.z; fy[4*m+3] = vy.w;
        }
        #pragma unroll
        for (int j = 0; j < 4; ++j) {
            float ax = 0.f, ay = 0.f, axx = 0.f, ayy = 0.f, axy = 0.f;
            #pragma unroll
            for (int k = 0; k < WS; ++k) {
                float w = GW[k];
                float xv = fx[j + k + 3], yv = fy[j + k + 3];
                ax  += w * xv;       ay  += w * yv;
                axx += w * xv * xv;  ayy += w * yv * yv;  axy += w * xv * yv;
            }
            int o = hoff(4 * c0 + j) + r;
            h[0][o] = ax;  h[1][o] = ay;
            h[2][o] = axx; h[3][o] = ayy; h[4][o] = axy;
        }
    }
    __syncthreads();

    // ---- vertical pass: 4 rows/thread, contiguous b128 reads ----
    const int c = tid & 31;                // output col
    const int q = tid >> 5;                // row group: rows 4q..4q+3
    const int ho = hoff(c) + 4 * q;        // 16B-aligned word offset

    float mu1[4], mu2[4], vxx[4], vyy[4], vxy[4];
    #pragma unroll
    for (int j = 0; j < 4; ++j) { mu1[j]=mu2[j]=vxx[j]=vyy[j]=vxy[j]=0.f; }

    #define VPASS(A, ACC)                                                    \
    {                                                                        \
        float f[16];                                                         \
        *(float4*)&f[0]  = *(const float4*)&h[A][ho];                        \
        *(float4*)&f[4]  = *(const float4*)&h[A][ho + 4];                    \
        *(float4*)&f[8]  = *(const float4*)&h[A][ho + 8];                    \
        *(float4*)&f[12] = *(const float4*)&h[A][ho + 12];                   \
        _Pragma("unroll")                                                    \
        for (int j = 0; j < 4; ++j) {                                        \
            _Pragma("unroll")                                                \
            for (int k = 0; k < WS; ++k) ACC[j] += GW[k] * f[j + k];         \
        }                                                                    \
    }
    VPASS(0, mu1) VPASS(1, mu2) VPASS(2, vxx) VPASS(3, vyy) VPASS(4, vxy)
    #undef VPASS

    float acc = 0.f;
    #pragma unroll
    for (int j = 0; j < 4; ++j) {
        float m1 = mu1[j], m2 = mu2[j];
        float m1s = m1 * m1, m2s = m2 * m2, m12 = m1 * m2;
        float s1 = vxx[j] - m1s, s2 = vyy[j] - m2s, s12 = vxy[j] - m12;
        float num = (2.f * m12 + SSIM_C1) * (2.f * s12 + SSIM_C2);
        float den = (m1s + m2s + SSIM_C1) * (s1 + s2 + SSIM_C2);
        acc += num / den;
    }

    // ---- block reduction ----
    #pragma unroll
    for (int off = 32; off > 0; off >>= 1)
        acc += __shfl_down(acc, off, 64);
    if ((tid & 63) == 0) red[tid >> 6] = acc;
    __syncthreads();
    if (tid == 0) {
        float s = red[0] + red[1] + red[2] + red[3];
        atomicAdd(out, -coef * s);
    }
}

} // namespace

extern "C" void kernel_launch(void* const* d_in, const int* in_sizes, int n_in,
                              void* d_out, int out_size, void* d_ws, size_t ws_size,
                              hipStream_t stream)
{
    const float* pred = (const float*)d_in[0];
    const float* targ = (const float*)d_in[1];
    float* out = (float*)d_out;

    const int N = 64;
    float* p1 = (float*)d_ws;                        // 64*256*256 fp32
    float* t1 = p1 + (size_t)N * 256 * 256;
    float* p2 = t1 + (size_t)N * 256 * 256;          // 64*128*128 fp32
    float* t2 = p2 + (size_t)N * 128 * 128;

    hipLaunchKernelGGL(init_out, dim3(1), dim3(1), 0, stream, out);

    const dim3 blk(256);
    hipLaunchKernelGGL((ssim_kernel<true>), dim3(512 / OT, 512 / OT, N), blk, 0, stream,
                       pred, targ, out, 0.5f / (N * 512.f * 512.f), p1, t1, 512, 512);
    hipLaunchKernelGGL((ssim_kernel<true>), dim3(256 / OT, 256 / OT, N), blk, 0, stream,
                       p1, t1, out, 0.3f / (N * 256.f * 256.f), p2, t2, 256, 256);
    hipLaunchKernelGGL((ssim_kernel<false>), dim3(128 / OT, 128 / OT, N), blk, 0, stream,
                       p2, t2, out, 0.2f / (N * 128.f * 128.f), nullptr, nullptr, 128, 128);
}

// Round 4
// 407.927 us; speedup vs baseline: 1.0480x; 1.0480x over previous
//
#include <hip/hip_runtime.h>

namespace {

constexpr int WS  = 11;
constexpr int RAD = 5;
constexpr int OT  = 32;            // output tile (square)
constexpr int HR  = OT + 2 * RAD;  // 42 h-rows per tile
constexpr float SSIM_C1 = 0.01f * 0.01f;
constexpr float SSIM_C2 = 0.03f * 0.03f;

// gaussian(sigma=1.5, ws=11); constexpr so unrolled accesses fold to literals
__device__ constexpr float GW[WS] = {
    0.00102838f, 0.00759876f, 0.03600077f, 0.10936069f, 0.21300553f,
    0.26601172f, 0.21300553f, 0.10936069f, 0.03600077f, 0.00759876f,
    0.00102838f};

// transposed h layout: logical (c in 0..31, r in 0..41) -> word c*44 + ((c>>3)<<2) + r
// stride 44 + 16B skew per 8 cols: per-16-lane phase of ds_read_b128 hits each
// bank exactly twice (free per m136).
constexpr int HWORDS = 32 * 44 + 16;   // 1424 words per quantity
__device__ __forceinline__ int hoff(int c) { return c * 44 + ((c >> 3) << 2); }

__global__ void init_out(float* out) { out[0] = 1.0f; }

template <bool POOL>
__global__ __launch_bounds__(256, 4)
void ssim_kernel(const float* __restrict__ X, const float* __restrict__ Y,
                 float* __restrict__ out, float coef,
                 float* __restrict__ PX, float* __restrict__ PY,
                 int H, int W)
{
    __shared__ float h[5][HWORDS];   // hx, hy, hxx, hyy, hxy (transposed)
    __shared__ float red[4];

    const int tid = threadIdx.x;
    const int n  = blockIdx.z;
    const int by = blockIdx.y * OT;
    const int bx = blockIdx.x * OT;
    const size_t plane = (size_t)H * W;
    const float* Xn = X + (size_t)n * plane;
    const float* Yn = Y + (size_t)n * plane;

    // ---- fused 2x2 avg-pool for next scale (global reads, L1-hot) ----
    if (POOL) {
        int pr = tid >> 4, pc = tid & 15;          // 16x16 pooled px per block
        int gr = by + 2 * pr, gc = bx + 2 * pc;
        const float* x0 = Xn + (size_t)gr * W + gc;
        const float* y0 = Yn + (size_t)gr * W + gc;
        float2 xa = *(const float2*)x0, xb = *(const float2*)(x0 + W);
        float2 ya = *(const float2*)y0, yb = *(const float2*)(y0 + W);
        int Wp = W >> 1;
        size_t po = (size_t)n * (size_t)(H >> 1) * Wp
                  + (size_t)((by >> 1) + pr) * Wp + ((bx >> 1) + pc);
        PX[po] = 0.25f * (xa.x + xa.y + xb.x + xb.y);
        PY[po] = 0.25f * (ya.x + ya.y + yb.x + yb.y);
    }

    // ---- horizontal pass: branch-free batched loads, 4 cols/thread ----
    // task idx = c0*42 + r. All 10 float4 loads are UNCONDITIONAL (addresses
    // clamped into the image) so they issue back-to-back -> 10 KB in flight
    // per wave; border zeros applied as masks at unpack (W%4==0 -> each
    // 4-aligned float4 is fully inside or fully outside).
    for (int idx = tid; idx < 8 * HR; idx += 256) {
        int c0 = idx / HR;                 // 0..7  (output cols 4c0..4c0+3)
        int r  = idx - c0 * HR;            // 0..41
        int gr = by + r - RAD;
        float rmask = ((unsigned)gr < (unsigned)H) ? 1.f : 0.f;
        int grc = min(max(gr, 0), H - 1);
        const float* xrow = Xn + (size_t)grc * W;
        const float* yrow = Yn + (size_t)grc * W;
        int gb = bx + 4 * c0 - 8;          // 4-aligned

        float4 vx[5], vy[5];
        float msk[5];
        #pragma unroll
        for (int m = 0; m < 5; ++m) {
            int gc = gb + 4 * m;
            msk[m] = ((unsigned)gc < (unsigned)W) ? rmask : 0.f;
            int gcc = min(max(gc, 0), W - 4);
            vx[m] = *(const float4*)(xrow + gcc);
            vy[m] = *(const float4*)(yrow + gcc);
        }

        float fx[20], fy[20];
        #pragma unroll
        for (int m = 0; m < 5; ++m) {
            float mm = msk[m];
            fx[4*m]   = vx[m].x * mm; fx[4*m+1] = vx[m].y * mm;
            fx[4*m+2] = vx[m].z * mm; fx[4*m+3] = vx[m].w * mm;
            fy[4*m]   = vy[m].x * mm; fy[4*m+1] = vy[m].y * mm;
            fy[4*m+2] = vy[m].z * mm; fy[4*m+3] = vy[m].w * mm;
        }

        #pragma unroll
        for (int j = 0; j < 4; ++j) {
            float ax = 0.f, ay = 0.f, axx = 0.f, ayy = 0.f, axy = 0.f;
            #pragma unroll
            for (int k = 0; k < WS; ++k) {
                float w = GW[k];
                float xv = fx[j + k + 3], yv = fy[j + k + 3];
                float tx = w * xv, ty = w * yv;
                ax  += tx;       ay  += ty;
                axx += tx * xv;  ayy += ty * yv;  axy += tx * yv;
            }
            int o = hoff(4 * c0 + j) + r;
            h[0][o] = ax;  h[1][o] = ay;
            h[2][o] = axx; h[3][o] = ayy; h[4][o] = axy;
        }
    }
    __syncthreads();

    // ---- vertical pass: 4 rows/thread, contiguous b128 reads ----
    const int c = tid & 31;                // output col
    const int q = tid >> 5;                // row group: rows 4q..4q+3
    const int ho = hoff(c) + 4 * q;        // 16B-aligned word offset

    float mu1[4], mu2[4], vxx[4], vyy[4], vxy[4];
    #pragma unroll
    for (int j = 0; j < 4; ++j) { mu1[j]=mu2[j]=vxx[j]=vyy[j]=vxy[j]=0.f; }

    #define VPASS(A, ACC)                                                    \
    {                                                                        \
        float f[16];                                                         \
        *(float4*)&f[0]  = *(const float4*)&h[A][ho];                        \
        *(float4*)&f[4]  = *(const float4*)&h[A][ho + 4];                    \
        *(float4*)&f[8]  = *(const float4*)&h[A][ho + 8];                    \
        *(float4*)&f[12] = *(const float4*)&h[A][ho + 12];                   \
        _Pragma("unroll")                                                    \
        for (int j = 0; j < 4; ++j) {                                        \
            _Pragma("unroll")                                                \
            for (int k = 0; k < WS; ++k) ACC[j] += GW[k] * f[j + k];         \
        }                                                                    \
    }
    VPASS(0, mu1) VPASS(1, mu2) VPASS(2, vxx) VPASS(3, vyy) VPASS(4, vxy)
    #undef VPASS

    float acc = 0.f;
    #pragma unroll
    for (int j = 0; j < 4; ++j) {
        float m1 = mu1[j], m2 = mu2[j];
        float m1s = m1 * m1, m2s = m2 * m2, m12 = m1 * m2;
        float s1 = vxx[j] - m1s, s2 = vyy[j] - m2s, s12 = vxy[j] - m12;
        float num = (2.f * m12 + SSIM_C1) * (2.f * s12 + SSIM_C2);
        float den = (m1s + m2s + SSIM_C1) * (s1 + s2 + SSIM_C2);
        acc += num / den;
    }

    // ---- block reduction ----
    #pragma unroll
    for (int off = 32; off > 0; off >>= 1)
        acc += __shfl_down(acc, off, 64);
    if ((tid & 63) == 0) red[tid >> 6] = acc;
    __syncthreads();
    if (tid == 0) {
        float s = red[0] + red[1] + red[2] + red[3];
        atomicAdd(out, -coef * s);
    }
}

} // namespace

extern "C" void kernel_launch(void* const* d_in, const int* in_sizes, int n_in,
                              void* d_out, int out_size, void* d_ws, size_t ws_size,
                              hipStream_t stream)
{
    const float* pred = (const float*)d_in[0];
    const float* targ = (const float*)d_in[1];
    float* out = (float*)d_out;

    const int N = 64;
    float* p1 = (float*)d_ws;                        // 64*256*256 fp32
    float* t1 = p1 + (size_t)N * 256 * 256;
    float* p2 = t1 + (size_t)N * 256 * 256;          // 64*128*128 fp32
    float* t2 = p2 + (size_t)N * 128 * 128;

    hipLaunchKernelGGL(init_out, dim3(1), dim3(1), 0, stream, out);

    const dim3 blk(256);
    hipLaunchKernelGGL((ssim_kernel<true>), dim3(512 / OT, 512 / OT, N), blk, 0, stream,
                       pred, targ, out, 0.5f / (N * 512.f * 512.f), p1, t1, 512, 512);
    hipLaunchKernelGGL((ssim_kernel<true>), dim3(256 / OT, 256 / OT, N), blk, 0, stream,
                       p1, t1, out, 0.3f / (N * 256.f * 256.f), p2, t2, 256, 256);
    hipLaunchKernelGGL((ssim_kernel<false>), dim3(128 / OT, 128 / OT, N), blk, 0, stream,
                       p2, t2, out, 0.2f / (N * 128.f * 128.f), nullptr, nullptr, 128, 128);
}